// Round 1
// baseline (247.601 us; speedup 1.0000x reference)
//
#include <hip/hip_runtime.h>
#include <hip/hip_bf16.h>

static constexpr int NN = 50000;   // nodes
static constexpr int NE = 800000;  // edges
static constexpr int NG = 512;     // graphs
static constexpr int NB = 196;     // 196*256 >= NN
static constexpr int GEMM_BLOCKS = (NN + 63) / 64;    // 782

__device__ __forceinline__ float bfu(ushort u) {
    return __uint_as_float((unsigned)u << 16);
}
__device__ __forceinline__ ushort fbf(float f) {
    return __hip_bfloat16_raw(__float2bfloat16(f)).x;
}

// ---------------- utility ----------------

__global__ void zero_kernel(float* __restrict__ p, int n) {
    int i = blockIdx.x * blockDim.x + threadIdx.x;
    if (i < n) p[i] = 0.f;
}

// ---------------- shared GEMM body: X [NN,K] @ W [K,64] -> out bf16 ----------------
// 64 rows/block, LDS-staged X + K-chunked W (16 KB), 16x16 threads, 4x4 register tile.
// LDS total 33792 B -> 4 blocks/CU (vs 50 KB/3 blocks with full-W staging).
template <int K, bool BF16IN>
__device__ __forceinline__ void gemm_body(const void* __restrict__ Xv,
                                          const float* __restrict__ W,
                                          ushort* __restrict__ out,
                                          int row0, float Xs[][68], float Ws[][64]) {
    int tx = threadIdx.x & 15, ty = threadIdx.x >> 4;
    float acc[4][4] = {};
    for (int kb = 0; kb < K; kb += 64) {
        __syncthreads();
        // stage W chunk: 64 k x 64 out = 1024 float4, coalesced
        for (int i = threadIdx.x; i < 1024; i += 256) {
            int kk = i >> 4, c4 = i & 15;
            *(float4*)&Ws[kk][c4 * 4] = *(const float4*)&W[(kb + kk) * 64 + c4 * 4];
        }
        if constexpr (BF16IN) {
            const ushort* X = (const ushort*)Xv;
            for (int i = threadIdx.x; i < 512; i += 256) {   // 64 rows x 8 groups of 8 ch
                int r = i >> 3, g = i & 7;
                int gr = row0 + r; if (gr >= NN) gr = NN - 1;
                uint4 v = *(const uint4*)(X + (long long)gr * K + kb + g * 8);
                float4 f0, f1;
                f0.x = __uint_as_float(v.x << 16); f0.y = __uint_as_float(v.x & 0xffff0000u);
                f0.z = __uint_as_float(v.y << 16); f0.w = __uint_as_float(v.y & 0xffff0000u);
                f1.x = __uint_as_float(v.z << 16); f1.y = __uint_as_float(v.z & 0xffff0000u);
                f1.z = __uint_as_float(v.w << 16); f1.w = __uint_as_float(v.w & 0xffff0000u);
                *(float4*)&Xs[r][g * 8] = f0;
                *(float4*)&Xs[r][g * 8 + 4] = f1;
            }
        } else {
            const float* X = (const float*)Xv;
            for (int i = threadIdx.x; i < 1024; i += 256) {  // 64 rows x 16 float4
                int r = i >> 4, k4 = i & 15;
                int gr = row0 + r; if (gr >= NN) gr = NN - 1;
                float4 v = *(const float4*)(X + (long long)gr * K + kb + k4 * 4);
                *(float4*)&Xs[r][k4 * 4] = v;
            }
        }
        __syncthreads();
#pragma unroll 16
        for (int k = 0; k < 64; ++k) {
            float4 wv = *(const float4*)&Ws[k][tx * 4];
            float x0 = Xs[ty * 4 + 0][k];
            float x1 = Xs[ty * 4 + 1][k];
            float x2 = Xs[ty * 4 + 2][k];
            float x3 = Xs[ty * 4 + 3][k];
            acc[0][0] = fmaf(x0, wv.x, acc[0][0]); acc[0][1] = fmaf(x0, wv.y, acc[0][1]);
            acc[0][2] = fmaf(x0, wv.z, acc[0][2]); acc[0][3] = fmaf(x0, wv.w, acc[0][3]);
            acc[1][0] = fmaf(x1, wv.x, acc[1][0]); acc[1][1] = fmaf(x1, wv.y, acc[1][1]);
            acc[1][2] = fmaf(x1, wv.z, acc[1][2]); acc[1][3] = fmaf(x1, wv.w, acc[1][3]);
            acc[2][0] = fmaf(x2, wv.x, acc[2][0]); acc[2][1] = fmaf(x2, wv.y, acc[2][1]);
            acc[2][2] = fmaf(x2, wv.z, acc[2][2]); acc[2][3] = fmaf(x2, wv.w, acc[2][3]);
            acc[3][0] = fmaf(x3, wv.x, acc[3][0]); acc[3][1] = fmaf(x3, wv.y, acc[3][1]);
            acc[3][2] = fmaf(x3, wv.z, acc[3][2]); acc[3][3] = fmaf(x3, wv.w, acc[3][3]);
        }
    }
#pragma unroll
    for (int j = 0; j < 4; ++j) {
        int r = row0 + ty * 4 + j;
        if (r < NN) {
            ushort4 sv;
            sv.x = fbf(acc[j][0]); sv.y = fbf(acc[j][1]);
            sv.z = fbf(acc[j][2]); sv.w = fbf(acc[j][3]);
            *(ushort4*)(out + (long long)r * 64 + tx * 4) = sv;
        }
    }
}

// ---------------- fused: hist64 grid-stride prologue + gemm128 -------------------------
// Each of the 782 GEMM blocks first processes ~4 edges/thread of the atomic histogram
// (order-independent: atomic return value supplies a unique rank regardless of timing),
// then runs its GEMM tile. All 782 blocks are co-resident at 4 blocks/CU, so the
// latency-bound atomic phase runs at full machine width and overlaps neighboring
// blocks' GEMM compute.
__global__ __launch_bounds__(256) void hist_gemm_kernel(const int* __restrict__ dst,
                                                        const float* __restrict__ ew,
                                                        unsigned long long* __restrict__ h,
                                                        int* __restrict__ rank,
                                                        const float* __restrict__ X,
                                                        const float* __restrict__ W,
                                                        ushort* __restrict__ out) {
    __shared__ float Xs[64][68];      // 2-way conflicts only (free)
    __shared__ float Ws[64][64];      // K-chunk of W
    for (int e = blockIdx.x * 256 + threadIdx.x; e < NE; e += GEMM_BLOCKS * 256) {
        // one 64-bit atomic per edge: count in [40:64), sum(ew) fixed-point 2^-20 in [0:40)
        // returned old count = edge's rank within its dst group (free CSR fill counter)
        int d = dst[e];
        unsigned int fx = __float2uint_rn(ew[e] * 1048576.0f);
        unsigned long long pack = (1ULL << 40) | (unsigned long long)fx;
        unsigned long long old = atomicAdd(&h[d], pack);
        rank[e] = (int)(old >> 40);
    }
    gemm_body<128, false>(X, W, out, blockIdx.x * 64, Xs, Ws);
}

// standalone GEMM for layer 2 (bf16 input)
template <int K, bool BF16IN>
__global__ __launch_bounds__(256) void gemm_kernel(const void* __restrict__ Xv,
                                                   const float* __restrict__ W,
                                                   ushort* __restrict__ out) {
    __shared__ float Xs[64][68];
    __shared__ float Ws[64][64];
    gemm_body<K, BF16IN>(Xv, W, out, blockIdx.x * 64, Xs, Ws);
}

// fused: dinv computation + per-block count reduction (scan phase A)
__global__ __launch_bounds__(256) void dinv_scanA_kernel(const unsigned long long* __restrict__ h,
                                                         float* __restrict__ dinv,
                                                         int* __restrict__ partial) {
    int i = blockIdx.x * 256 + threadIdx.x;
    int cnt = 0;
    if (i < NN) {
        unsigned long long v = h[i];
        cnt = (int)(v >> 40);
        float deg = (float)(v & ((1ULL << 40) - 1)) * (1.0f / 1048576.0f) + 1.0f;
        dinv[i] = 1.0f / sqrtf(deg);
    }
    __shared__ int wsum[4];
    int lane = threadIdx.x & 63, wid = threadIdx.x >> 6;
    int v = cnt;
#pragma unroll
    for (int off = 32; off > 0; off >>= 1) v += __shfl_down(v, (unsigned)off, 64);
    if (lane == 0) wsum[wid] = v;
    __syncthreads();
    if (threadIdx.x == 0) partial[blockIdx.x] = wsum[0] + wsum[1] + wsum[2] + wsum[3];
}

__device__ __forceinline__ int block_scan_inclusive(int v, int* wtot) {
    int lane = threadIdx.x & 63, wid = threadIdx.x >> 6;
    int inc = v;
#pragma unroll
    for (int off = 1; off < 64; off <<= 1) {
        int n = __shfl_up(inc, (unsigned)off, 64);
        if (lane >= off) inc += n;
    }
    if (lane == 63) wtot[wid] = inc;
    __syncthreads();
    int add = 0;
    for (int w = 0; w < wid; ++w) add += wtot[w];
    return inc + add;
}

// fused: per-block prefix of partials (scanB inlined) + rowptr finalize + graph bounds
__global__ __launch_bounds__(256) void scanC_bounds_kernel(const unsigned long long* __restrict__ h,
                                                           const int* __restrict__ partial,
                                                           int* __restrict__ rowptr,
                                                           const int* __restrict__ batch,
                                                           int* __restrict__ gbeg,
                                                           int* __restrict__ gend) {
    __shared__ int wtot[4];
    __shared__ int poff_s;
    int t = threadIdx.x;
    if (t < 64) {   // wave 0: poff = sum partial[0..bid-1]
        int s = 0;
        for (int i = t; i < (int)blockIdx.x; i += 64) s += partial[i];
#pragma unroll
        for (int off = 32; off > 0; off >>= 1) s += __shfl_down(s, (unsigned)off, 64);
        if (t == 0) poff_s = s;
    }
    int i = blockIdx.x * 256 + t;
    int v = (i < NN) ? (int)(h[i] >> 40) : 0;
    int incl = block_scan_inclusive(v, wtot);   // internal __syncthreads makes poff_s visible
    if (i < NN) {
        rowptr[i + 1] = poff_s + incl;
        int g = batch[i];
        if (i == 0 || batch[i - 1] != g) gbeg[g] = i;
        if (i == NN - 1 || batch[i + 1] != g) gend[g] = i + 1;
    }
    if (i == 0) rowptr[0] = 0;
}

// Atomic-free scatter: pos = rowptr[d] + rank[e]; epack[pos] = (src, dinv[s]*ew)
__global__ __launch_bounds__(256) void scatter_kernel(const int* __restrict__ src,
                                                      const int* __restrict__ dst,
                                                      const float* __restrict__ ew,
                                                      const float* __restrict__ dinv,
                                                      const int* __restrict__ rowptr,
                                                      const int* __restrict__ rank,
                                                      int2* __restrict__ epack) {
    int e = blockIdx.x * blockDim.x + threadIdx.x;
    if (e >= NE) return;
    int s = src[e], d = dst[e];
    int pos = rowptr[d] + rank[e];
    float coef = dinv[s] * ew[e];
    epack[pos] = make_int2(s, __float_as_int(coef));
}

// ---------------- CSR aggregation: one wave per node; quarter-waves x 4 ch/lane --------
// out[i,:] = bias + dinv[i]^2*xw[i,:] + dinv[i] * sum_j (dinv[s]*ew)_j * xw[src_j,:]
template <bool RELU>
__global__ __launch_bounds__(256) void agg_kernel(const ushort* __restrict__ xw,
                                                  const int* __restrict__ rowptr,
                                                  const int2* __restrict__ epack,
                                                  const float* __restrict__ dinv,
                                                  const float* __restrict__ bias,
                                                  ushort* __restrict__ out) {
    int node = blockIdx.x * 4 + (threadIdx.x >> 6);
    if (node >= NN) return;
    int lane = threadIdx.x & 63;
    int q = lane >> 4;       // edge slot within group of 4
    int l = lane & 15;       // channel group: ch 4l..4l+3
    int beg = rowptr[node], end = rowptr[node + 1];
    float a0 = 0.f, a1 = 0.f, a2 = 0.f, a3 = 0.f;
    float b0 = 0.f, b1 = 0.f, b2 = 0.f, b3 = 0.f;
    int j = beg + q;
    for (; j + 4 < end; j += 8) {
        int2 pA = epack[j];
        int2 pB = epack[j + 4];
        ushort4 uA = *(const ushort4*)(xw + pA.x * 64 + 4 * l);
        ushort4 uB = *(const ushort4*)(xw + pB.x * 64 + 4 * l);
        float wA = __int_as_float(pA.y);
        float wB = __int_as_float(pB.y);
        a0 = fmaf(wA, bfu(uA.x), a0); a1 = fmaf(wA, bfu(uA.y), a1);
        a2 = fmaf(wA, bfu(uA.z), a2); a3 = fmaf(wA, bfu(uA.w), a3);
        b0 = fmaf(wB, bfu(uB.x), b0); b1 = fmaf(wB, bfu(uB.y), b1);
        b2 = fmaf(wB, bfu(uB.z), b2); b3 = fmaf(wB, bfu(uB.w), b3);
    }
    if (j < end) {
        int2 pA = epack[j];
        ushort4 uA = *(const ushort4*)(xw + pA.x * 64 + 4 * l);
        float wA = __int_as_float(pA.y);
        a0 = fmaf(wA, bfu(uA.x), a0); a1 = fmaf(wA, bfu(uA.y), a1);
        a2 = fmaf(wA, bfu(uA.z), a2); a3 = fmaf(wA, bfu(uA.w), a3);
    }
    a0 += b0; a1 += b1; a2 += b2; a3 += b3;
    a0 += __shfl_xor(a0, 16); a0 += __shfl_xor(a0, 32);
    a1 += __shfl_xor(a1, 16); a1 += __shfl_xor(a1, 32);
    a2 += __shfl_xor(a2, 16); a2 += __shfl_xor(a2, 32);
    a3 += __shfl_xor(a3, 16); a3 += __shfl_xor(a3, 32);
    if (q == 0) {
        float di = dinv[node];
        float d2 = di * di;
        ushort4 us = *(const ushort4*)(xw + node * 64 + 4 * l);
        float4 bv = *(const float4*)(bias + 4 * l);
        float o0 = fmaf(di, a0, fmaf(d2, bfu(us.x), bv.x));
        float o1 = fmaf(di, a1, fmaf(d2, bfu(us.y), bv.y));
        float o2 = fmaf(di, a2, fmaf(d2, bfu(us.z), bv.z));
        float o3 = fmaf(di, a3, fmaf(d2, bfu(us.w), bv.w));
        if (RELU) {
            o0 = fmaxf(o0, 0.f); o1 = fmaxf(o1, 0.f);
            o2 = fmaxf(o2, 0.f); o3 = fmaxf(o3, 0.f);
        }
        ushort4 sv;
        sv.x = fbf(o0); sv.y = fbf(o1); sv.z = fbf(o2); sv.w = fbf(o3);
        *(ushort4*)(out + node * 64 + 4 * l) = sv;
    }
}

// ---------------- fused mean-pool + MLP head: 4 waves per graph (h is bf16) -----------
__global__ __launch_bounds__(256) void poolhead_kernel(const ushort* __restrict__ h,
                                                       const int* __restrict__ gbeg,
                                                       const int* __restrict__ gend,
                                                       const float* __restrict__ LW1,
                                                       const float* __restrict__ Lb1,
                                                       const float* __restrict__ LW2,
                                                       const float* __restrict__ Lb2,
                                                       float* __restrict__ out) {
    __shared__ float pp[4][64];
    __shared__ float p[64];
    __shared__ float t1[32];
    int g = blockIdx.x, t = threadIdx.x;
    int lane = t & 63, wid = t >> 6;
    int b = gbeg[g], e = gend[g];
    float acc = 0.f;
    for (int i = b + wid; i < e; i += 4) acc += bfu(h[i * 64 + lane]);
    pp[wid][lane] = acc;
    __syncthreads();
    if (t < 64) {
        float s = pp[0][t] + pp[1][t] + pp[2][t] + pp[3][t];
        p[t] = s / fmaxf((float)(e - b), 1.0f);
    }
    __syncthreads();
    if (t < 32) {
        float a = Lb1[t];
#pragma unroll
        for (int k = 0; k < 64; ++k) a = fmaf(p[k], LW1[k * 32 + t], a);
        t1[t] = a;
    }
    __syncthreads();
    if (t < 10) {
        float a = Lb2[t];
#pragma unroll
        for (int j = 0; j < 32; ++j) a = fmaf(t1[j], LW2[j * 10 + t], a);
        out[g * 10 + t] = a;
    }
}

// ---------------- launch ----------------

extern "C" void kernel_launch(void* const* d_in, const int* in_sizes, int n_in,
                              void* d_out, int out_size, void* d_ws, size_t ws_size,
                              hipStream_t stream) {
    const float* x     = (const float*)d_in[0];
    const int*   ei    = (const int*)d_in[1];   // [2, NE]
    const float* ew    = (const float*)d_in[2];
    const int*   batch = (const int*)d_in[3];
    const float* W1    = (const float*)d_in[4];
    const float* b1    = (const float*)d_in[5];
    const float* W2    = (const float*)d_in[6];
    const float* b2    = (const float*)d_in[7];
    const float* LW1   = (const float*)d_in[8];
    const float* Lb1   = (const float*)d_in[9];
    const float* LW2   = (const float*)d_in[10];
    const float* Lb2   = (const float*)d_in[11];

    const int* src = ei;
    const int* dst = ei + NE;

    // workspace layout (4-byte units)
    float* ws = (float*)d_ws;
    unsigned long long* h64 = (unsigned long long*)ws;  // [NN] ull: 0 .. 100096
    int*   gbeg   = (int*)(ws + 100096);       // [NG] -> 100608
    int*   gend   = (int*)(ws + 100608);       // [NG] -> 101120  (zero range ends here)
    float* dinv   = ws + 101120;               // [NN]   -> 151168
    int*   rowptr = (int*)(ws + 151168);       // [NN+1] -> 201216
    int*   partial= (int*)(ws + 201216);       // [NB]   -> 201472 (8B-aligned next)
    int2*  epack  = (int2*)(ws + 201472);      // [NE]   -> 1801472
    ushort* xwA   = (ushort*)(ws + 1801472);   // [NN*64] bf16: xw1, later xw2 -> 3401472
    ushort* h12   = (ushort*)(ws + 3401472);   // [NN*64] bf16: h1, later h2 -> 5001472
    int*   rank   = (int*)(ws + 5001472);      // [NE] (dead after scatter) -> 5801472
    // total 5801472 floats = 23.2 MB

    zero_kernel<<<(101120 + 255) / 256, 256, 0, stream>>>(ws, 101120);

    // hist64 (atomic CSR histogram, grid-strided) fused into gemm128 (x @ W1) blocks
    hist_gemm_kernel<<<GEMM_BLOCKS, 256, 0, stream>>>(dst, ew, h64, rank, x, W1, xwA);
    dinv_scanA_kernel<<<NB, 256, 0, stream>>>(h64, dinv, partial);
    scanC_bounds_kernel<<<NB, 256, 0, stream>>>(h64, partial, rowptr, batch, gbeg, gend);
    scatter_kernel<<<(NE + 255) / 256, 256, 0, stream>>>(src, dst, ew, dinv, rowptr, rank, epack);

    // ---- layer 1 aggregation ----
    agg_kernel<true><<<(NN + 3) / 4, 256, 0, stream>>>(xwA, rowptr, epack, dinv, b1, h12);

    // ---- layer 2 ----
    gemm_kernel<64, true><<<GEMM_BLOCKS, 256, 0, stream>>>(h12, W2, xwA);
    agg_kernel<false><<<(NN + 3) / 4, 256, 0, stream>>>(xwA, rowptr, epack, dinv, b2, h12);

    // ---- pool + head ----
    poolhead_kernel<<<NG, 256, 0, stream>>>(h12, gbeg, gend, LW1, Lb1, LW2, Lb2, (float*)d_out);
}

// Round 2
// 243.677 us; speedup vs baseline: 1.0161x; 1.0161x over previous
//
#include <hip/hip_runtime.h>
#include <hip/hip_bf16.h>

static constexpr int NN = 50000;   // nodes
static constexpr int NE = 800000;  // edges
static constexpr int NG = 512;     // graphs
static constexpr int NB = 196;     // 196*256 >= NN
static constexpr int GEMM_BLOCKS = (NN + 63) / 64;    // 782
static constexpr int HB = 128;     // dedicated histogram blocks (co-resident with GEMM)

__device__ __forceinline__ float bfu(ushort u) {
    return __uint_as_float((unsigned)u << 16);
}
__device__ __forceinline__ ushort fbf(float f) {
    return __hip_bfloat16_raw(__float2bfloat16(f)).x;
}

// ---------------- utility ----------------

__global__ void zero_kernel(float* __restrict__ p, int n) {
    int i = blockIdx.x * blockDim.x + threadIdx.x;
    if (i < n) p[i] = 0.f;
}

// ---------------- shared GEMM body: X [NN,K] @ W [K,64] -> out bf16 ----------------
// 64 rows/block, LDS-staged X + K-chunked W (16 KB), 16x16 threads, 4x4 register tile.
// Inner loop processes k in groups of 4 with ds_read_b128 only:
// 8 LDS instrs / 64 FMAs (vs 20 with scalar Xs reads) -> LDS pipe no longer dominates.
// FMA order per acc element is k-ascending, identical to the scalar version (bitexact).
template <int K, bool BF16IN>
__device__ __forceinline__ void gemm_body(const void* __restrict__ Xv,
                                          const float* __restrict__ W,
                                          ushort* __restrict__ out,
                                          int row0, float Xs[][68], float Ws[][64]) {
    int tx = threadIdx.x & 15, ty = threadIdx.x >> 4;
    float acc[4][4] = {};
    for (int kb = 0; kb < K; kb += 64) {
        __syncthreads();
        // stage W chunk: 64 k x 64 out = 1024 float4, coalesced
        for (int i = threadIdx.x; i < 1024; i += 256) {
            int kk = i >> 4, c4 = i & 15;
            *(float4*)&Ws[kk][c4 * 4] = *(const float4*)&W[(kb + kk) * 64 + c4 * 4];
        }
        if constexpr (BF16IN) {
            const ushort* X = (const ushort*)Xv;
            for (int i = threadIdx.x; i < 512; i += 256) {   // 64 rows x 8 groups of 8 ch
                int r = i >> 3, g = i & 7;
                int gr = row0 + r; if (gr >= NN) gr = NN - 1;
                uint4 v = *(const uint4*)(X + (long long)gr * K + kb + g * 8);
                float4 f0, f1;
                f0.x = __uint_as_float(v.x << 16); f0.y = __uint_as_float(v.x & 0xffff0000u);
                f0.z = __uint_as_float(v.y << 16); f0.w = __uint_as_float(v.y & 0xffff0000u);
                f1.x = __uint_as_float(v.z << 16); f1.y = __uint_as_float(v.z & 0xffff0000u);
                f1.z = __uint_as_float(v.w << 16); f1.w = __uint_as_float(v.w & 0xffff0000u);
                *(float4*)&Xs[r][g * 8] = f0;
                *(float4*)&Xs[r][g * 8 + 4] = f1;
            }
        } else {
            const float* X = (const float*)Xv;
            for (int i = threadIdx.x; i < 1024; i += 256) {  // 64 rows x 16 float4
                int r = i >> 4, k4 = i & 15;
                int gr = row0 + r; if (gr >= NN) gr = NN - 1;
                float4 v = *(const float4*)(X + (long long)gr * K + kb + k4 * 4);
                *(float4*)&Xs[r][k4 * 4] = v;
            }
        }
        __syncthreads();
#pragma unroll
        for (int k4 = 0; k4 < 16; ++k4) {
            float4 w0 = *(const float4*)&Ws[k4 * 4 + 0][tx * 4];
            float4 w1 = *(const float4*)&Ws[k4 * 4 + 1][tx * 4];
            float4 w2 = *(const float4*)&Ws[k4 * 4 + 2][tx * 4];
            float4 w3 = *(const float4*)&Ws[k4 * 4 + 3][tx * 4];
            float4 x0 = *(const float4*)&Xs[ty * 4 + 0][k4 * 4];
            float4 x1 = *(const float4*)&Xs[ty * 4 + 1][k4 * 4];
            float4 x2 = *(const float4*)&Xs[ty * 4 + 2][k4 * 4];
            float4 x3 = *(const float4*)&Xs[ty * 4 + 3][k4 * 4];
#define GCN_ROW(j, xv) \
            acc[j][0]=fmaf(xv.x,w0.x,acc[j][0]); acc[j][1]=fmaf(xv.x,w0.y,acc[j][1]); \
            acc[j][2]=fmaf(xv.x,w0.z,acc[j][2]); acc[j][3]=fmaf(xv.x,w0.w,acc[j][3]); \
            acc[j][0]=fmaf(xv.y,w1.x,acc[j][0]); acc[j][1]=fmaf(xv.y,w1.y,acc[j][1]); \
            acc[j][2]=fmaf(xv.y,w1.z,acc[j][2]); acc[j][3]=fmaf(xv.y,w1.w,acc[j][3]); \
            acc[j][0]=fmaf(xv.z,w2.x,acc[j][0]); acc[j][1]=fmaf(xv.z,w2.y,acc[j][1]); \
            acc[j][2]=fmaf(xv.z,w2.z,acc[j][2]); acc[j][3]=fmaf(xv.z,w2.w,acc[j][3]); \
            acc[j][0]=fmaf(xv.w,w3.x,acc[j][0]); acc[j][1]=fmaf(xv.w,w3.y,acc[j][1]); \
            acc[j][2]=fmaf(xv.w,w3.z,acc[j][2]); acc[j][3]=fmaf(xv.w,w3.w,acc[j][3]);
            GCN_ROW(0, x0)
            GCN_ROW(1, x1)
            GCN_ROW(2, x2)
            GCN_ROW(3, x3)
#undef GCN_ROW
        }
    }
#pragma unroll
    for (int j = 0; j < 4; ++j) {
        int r = row0 + ty * 4 + j;
        if (r < NN) {
            ushort4 sv;
            sv.x = fbf(acc[j][0]); sv.y = fbf(acc[j][1]);
            sv.z = fbf(acc[j][2]); sv.w = fbf(acc[j][3]);
            *(ushort4*)(out + (long long)r * 64 + tx * 4) = sv;
        }
    }
}

// ---------------- fused: role-split hist blocks || gemm blocks -------------------------
// Blocks [0, HB) grid-stride the full edge list issuing the atomic histogram; blocks
// [HB, HB+GEMM_BLOCKS) run the GEMM. All 910 blocks are co-resident (33.8 KB LDS ->
// 4 blocks/CU = 1024 slots), so the atomic-throughput-bound histogram stream runs
// CONCURRENTLY with the GEMM's LDS/VALU work instead of phase-serializing with it.
__global__ __launch_bounds__(256) void hist_gemm_kernel(const int* __restrict__ dst,
                                                        const float* __restrict__ ew,
                                                        unsigned long long* __restrict__ h,
                                                        int* __restrict__ rank,
                                                        const float* __restrict__ X,
                                                        const float* __restrict__ W,
                                                        ushort* __restrict__ out) {
    __shared__ float Xs[64][68];      // 2-way conflicts only (free)
    __shared__ float Ws[64][64];      // K-chunk of W
    if (blockIdx.x < HB) {
        // one 64-bit atomic per edge: count in [40:64), sum(ew) fixed-point 2^-20 in [0:40)
        // returned old count = edge's rank within its dst group (free CSR fill counter)
        for (int e = blockIdx.x * 256 + threadIdx.x; e < NE; e += HB * 256) {
            int d = dst[e];
            unsigned int fx = __float2uint_rn(ew[e] * 1048576.0f);
            unsigned long long pack = (1ULL << 40) | (unsigned long long)fx;
            unsigned long long old = atomicAdd(&h[d], pack);
            rank[e] = (int)(old >> 40);
        }
        return;
    }
    gemm_body<128, false>(X, W, out, (blockIdx.x - HB) * 64, Xs, Ws);
}

// standalone GEMM for layer 2 (bf16 input)
template <int K, bool BF16IN>
__global__ __launch_bounds__(256) void gemm_kernel(const void* __restrict__ Xv,
                                                   const float* __restrict__ W,
                                                   ushort* __restrict__ out) {
    __shared__ float Xs[64][68];
    __shared__ float Ws[64][64];
    gemm_body<K, BF16IN>(Xv, W, out, blockIdx.x * 64, Xs, Ws);
}

// fused: dinv computation + per-block count reduction (scan phase A)
__global__ __launch_bounds__(256) void dinv_scanA_kernel(const unsigned long long* __restrict__ h,
                                                         float* __restrict__ dinv,
                                                         int* __restrict__ partial) {
    int i = blockIdx.x * 256 + threadIdx.x;
    int cnt = 0;
    if (i < NN) {
        unsigned long long v = h[i];
        cnt = (int)(v >> 40);
        float deg = (float)(v & ((1ULL << 40) - 1)) * (1.0f / 1048576.0f) + 1.0f;
        dinv[i] = 1.0f / sqrtf(deg);
    }
    __shared__ int wsum[4];
    int lane = threadIdx.x & 63, wid = threadIdx.x >> 6;
    int v = cnt;
#pragma unroll
    for (int off = 32; off > 0; off >>= 1) v += __shfl_down(v, (unsigned)off, 64);
    if (lane == 0) wsum[wid] = v;
    __syncthreads();
    if (threadIdx.x == 0) partial[blockIdx.x] = wsum[0] + wsum[1] + wsum[2] + wsum[3];
}

__device__ __forceinline__ int block_scan_inclusive(int v, int* wtot) {
    int lane = threadIdx.x & 63, wid = threadIdx.x >> 6;
    int inc = v;
#pragma unroll
    for (int off = 1; off < 64; off <<= 1) {
        int n = __shfl_up(inc, (unsigned)off, 64);
        if (lane >= off) inc += n;
    }
    if (lane == 63) wtot[wid] = inc;
    __syncthreads();
    int add = 0;
    for (int w = 0; w < wid; ++w) add += wtot[w];
    return inc + add;
}

// fused: per-block prefix of partials (scanB inlined) + rowptr finalize + graph bounds
__global__ __launch_bounds__(256) void scanC_bounds_kernel(const unsigned long long* __restrict__ h,
                                                           const int* __restrict__ partial,
                                                           int* __restrict__ rowptr,
                                                           const int* __restrict__ batch,
                                                           int* __restrict__ gbeg,
                                                           int* __restrict__ gend) {
    __shared__ int wtot[4];
    __shared__ int poff_s;
    int t = threadIdx.x;
    if (t < 64) {   // wave 0: poff = sum partial[0..bid-1]
        int s = 0;
        for (int i = t; i < (int)blockIdx.x; i += 64) s += partial[i];
#pragma unroll
        for (int off = 32; off > 0; off >>= 1) s += __shfl_down(s, (unsigned)off, 64);
        if (t == 0) poff_s = s;
    }
    int i = blockIdx.x * 256 + t;
    int v = (i < NN) ? (int)(h[i] >> 40) : 0;
    int incl = block_scan_inclusive(v, wtot);   // internal __syncthreads makes poff_s visible
    if (i < NN) {
        rowptr[i + 1] = poff_s + incl;
        int g = batch[i];
        if (i == 0 || batch[i - 1] != g) gbeg[g] = i;
        if (i == NN - 1 || batch[i + 1] != g) gend[g] = i + 1;
    }
    if (i == 0) rowptr[0] = 0;
}

// Atomic-free scatter: pos = rowptr[d] + rank[e]; epack[pos] = (src, dinv[s]*ew)
__global__ __launch_bounds__(256) void scatter_kernel(const int* __restrict__ src,
                                                      const int* __restrict__ dst,
                                                      const float* __restrict__ ew,
                                                      const float* __restrict__ dinv,
                                                      const int* __restrict__ rowptr,
                                                      const int* __restrict__ rank,
                                                      int2* __restrict__ epack) {
    int e = blockIdx.x * blockDim.x + threadIdx.x;
    if (e >= NE) return;
    int s = src[e], d = dst[e];
    int pos = rowptr[d] + rank[e];
    float coef = dinv[s] * ew[e];
    epack[pos] = make_int2(s, __float_as_int(coef));
}

// ---------------- CSR aggregation: one wave per node; quarter-waves x 4 ch/lane --------
// out[i,:] = bias + dinv[i]^2*xw[i,:] + dinv[i] * sum_j (dinv[s]*ew)_j * xw[src_j,:]
template <bool RELU>
__global__ __launch_bounds__(256) void agg_kernel(const ushort* __restrict__ xw,
                                                  const int* __restrict__ rowptr,
                                                  const int2* __restrict__ epack,
                                                  const float* __restrict__ dinv,
                                                  const float* __restrict__ bias,
                                                  ushort* __restrict__ out) {
    int node = blockIdx.x * 4 + (threadIdx.x >> 6);
    if (node >= NN) return;
    int lane = threadIdx.x & 63;
    int q = lane >> 4;       // edge slot within group of 4
    int l = lane & 15;       // channel group: ch 4l..4l+3
    int beg = rowptr[node], end = rowptr[node + 1];
    float a0 = 0.f, a1 = 0.f, a2 = 0.f, a3 = 0.f;
    float b0 = 0.f, b1 = 0.f, b2 = 0.f, b3 = 0.f;
    int j = beg + q;
    for (; j + 4 < end; j += 8) {
        int2 pA = epack[j];
        int2 pB = epack[j + 4];
        ushort4 uA = *(const ushort4*)(xw + pA.x * 64 + 4 * l);
        ushort4 uB = *(const ushort4*)(xw + pB.x * 64 + 4 * l);
        float wA = __int_as_float(pA.y);
        float wB = __int_as_float(pB.y);
        a0 = fmaf(wA, bfu(uA.x), a0); a1 = fmaf(wA, bfu(uA.y), a1);
        a2 = fmaf(wA, bfu(uA.z), a2); a3 = fmaf(wA, bfu(uA.w), a3);
        b0 = fmaf(wB, bfu(uB.x), b0); b1 = fmaf(wB, bfu(uB.y), b1);
        b2 = fmaf(wB, bfu(uB.z), b2); b3 = fmaf(wB, bfu(uB.w), b3);
    }
    if (j < end) {
        int2 pA = epack[j];
        ushort4 uA = *(const ushort4*)(xw + pA.x * 64 + 4 * l);
        float wA = __int_as_float(pA.y);
        a0 = fmaf(wA, bfu(uA.x), a0); a1 = fmaf(wA, bfu(uA.y), a1);
        a2 = fmaf(wA, bfu(uA.z), a2); a3 = fmaf(wA, bfu(uA.w), a3);
    }
    a0 += b0; a1 += b1; a2 += b2; a3 += b3;
    a0 += __shfl_xor(a0, 16); a0 += __shfl_xor(a0, 32);
    a1 += __shfl_xor(a1, 16); a1 += __shfl_xor(a1, 32);
    a2 += __shfl_xor(a2, 16); a2 += __shfl_xor(a2, 32);
    a3 += __shfl_xor(a3, 16); a3 += __shfl_xor(a3, 32);
    if (q == 0) {
        float di = dinv[node];
        float d2 = di * di;
        ushort4 us = *(const ushort4*)(xw + node * 64 + 4 * l);
        float4 bv = *(const float4*)(bias + 4 * l);
        float o0 = fmaf(di, a0, fmaf(d2, bfu(us.x), bv.x));
        float o1 = fmaf(di, a1, fmaf(d2, bfu(us.y), bv.y));
        float o2 = fmaf(di, a2, fmaf(d2, bfu(us.z), bv.z));
        float o3 = fmaf(di, a3, fmaf(d2, bfu(us.w), bv.w));
        if (RELU) {
            o0 = fmaxf(o0, 0.f); o1 = fmaxf(o1, 0.f);
            o2 = fmaxf(o2, 0.f); o3 = fmaxf(o3, 0.f);
        }
        ushort4 sv;
        sv.x = fbf(o0); sv.y = fbf(o1); sv.z = fbf(o2); sv.w = fbf(o3);
        *(ushort4*)(out + node * 64 + 4 * l) = sv;
    }
}

// ---------------- fused mean-pool + MLP head: 4 waves per graph (h is bf16) -----------
__global__ __launch_bounds__(256) void poolhead_kernel(const ushort* __restrict__ h,
                                                       const int* __restrict__ gbeg,
                                                       const int* __restrict__ gend,
                                                       const float* __restrict__ LW1,
                                                       const float* __restrict__ Lb1,
                                                       const float* __restrict__ LW2,
                                                       const float* __restrict__ Lb2,
                                                       float* __restrict__ out) {
    __shared__ float pp[4][64];
    __shared__ float p[64];
    __shared__ float t1[32];
    int g = blockIdx.x, t = threadIdx.x;
    int lane = t & 63, wid = t >> 6;
    int b = gbeg[g], e = gend[g];
    float acc = 0.f;
    for (int i = b + wid; i < e; i += 4) acc += bfu(h[i * 64 + lane]);
    pp[wid][lane] = acc;
    __syncthreads();
    if (t < 64) {
        float s = pp[0][t] + pp[1][t] + pp[2][t] + pp[3][t];
        p[t] = s / fmaxf((float)(e - b), 1.0f);
    }
    __syncthreads();
    if (t < 32) {
        float a = Lb1[t];
#pragma unroll
        for (int k = 0; k < 64; ++k) a = fmaf(p[k], LW1[k * 32 + t], a);
        t1[t] = a;
    }
    __syncthreads();
    if (t < 10) {
        float a = Lb2[t];
#pragma unroll
        for (int j = 0; j < 32; ++j) a = fmaf(t1[j], LW2[j * 10 + t], a);
        out[g * 10 + t] = a;
    }
}

// ---------------- launch ----------------

extern "C" void kernel_launch(void* const* d_in, const int* in_sizes, int n_in,
                              void* d_out, int out_size, void* d_ws, size_t ws_size,
                              hipStream_t stream) {
    const float* x     = (const float*)d_in[0];
    const int*   ei    = (const int*)d_in[1];   // [2, NE]
    const float* ew    = (const float*)d_in[2];
    const int*   batch = (const int*)d_in[3];
    const float* W1    = (const float*)d_in[4];
    const float* b1    = (const float*)d_in[5];
    const float* W2    = (const float*)d_in[6];
    const float* b2    = (const float*)d_in[7];
    const float* LW1   = (const float*)d_in[8];
    const float* Lb1   = (const float*)d_in[9];
    const float* LW2   = (const float*)d_in[10];
    const float* Lb2   = (const float*)d_in[11];

    const int* src = ei;
    const int* dst = ei + NE;

    // workspace layout (4-byte units)
    float* ws = (float*)d_ws;
    unsigned long long* h64 = (unsigned long long*)ws;  // [NN] ull: 0 .. 100096
    int*   gbeg   = (int*)(ws + 100096);       // [NG] -> 100608
    int*   gend   = (int*)(ws + 100608);       // [NG] -> 101120  (zero range ends here)
    float* dinv   = ws + 101120;               // [NN]   -> 151168
    int*   rowptr = (int*)(ws + 151168);       // [NN+1] -> 201216
    int*   partial= (int*)(ws + 201216);       // [NB]   -> 201472 (8B-aligned next)
    int2*  epack  = (int2*)(ws + 201472);      // [NE]   -> 1801472
    ushort* xwA   = (ushort*)(ws + 1801472);   // [NN*64] bf16: xw1, later xw2 -> 3401472
    ushort* h12   = (ushort*)(ws + 3401472);   // [NN*64] bf16: h1, later h2 -> 5001472
    int*   rank   = (int*)(ws + 5001472);      // [NE] (dead after scatter) -> 5801472
    // total 5801472 floats = 23.2 MB

    zero_kernel<<<(101120 + 255) / 256, 256, 0, stream>>>(ws, 101120);

    // role-split: blocks [0,HB) = atomic histogram (grid-stride), rest = x @ W1 GEMM
    hist_gemm_kernel<<<HB + GEMM_BLOCKS, 256, 0, stream>>>(dst, ew, h64, rank, x, W1, xwA);
    dinv_scanA_kernel<<<NB, 256, 0, stream>>>(h64, dinv, partial);
    scanC_bounds_kernel<<<NB, 256, 0, stream>>>(h64, partial, rowptr, batch, gbeg, gend);
    scatter_kernel<<<(NE + 255) / 256, 256, 0, stream>>>(src, dst, ew, dinv, rowptr, rank, epack);

    // ---- layer 1 aggregation ----
    agg_kernel<true><<<(NN + 3) / 4, 256, 0, stream>>>(xwA, rowptr, epack, dinv, b1, h12);

    // ---- layer 2 ----
    gemm_kernel<64, true><<<GEMM_BLOCKS, 256, 0, stream>>>(h12, W2, xwA);
    agg_kernel<false><<<(NN + 3) / 4, 256, 0, stream>>>(xwA, rowptr, epack, dinv, b2, h12);

    // ---- pool + head ----
    poolhead_kernel<<<NG, 256, 0, stream>>>(h12, gbeg, gend, LW1, Lb1, LW2, Lb2, (float*)d_out);
}